// Round 3
// baseline (614.536 us; speedup 1.0000x reference)
//
#include <hip/hip_runtime.h>
#include <cstdint>
#include <cstddef>

// ============================================================================
// ResMLP fused kernel for MI355X (gfx950) — round 11
//
// Shape change vs r10: 64 batch rows per wave (two 32-row B-frag sets), so
// each A-frag (weight) ds_read_b128 feeds TWO MFMAs -> LDS-read traffic per
// FLOP halves; MFMA pipe becomes the binding resource (~50 us floor).
//  - grid 256 x 256 thr, ONE block/CU, 4 waves, 256 batch rows/block.
//  - LDS = ring of 6 x 25.6KB half-panel slots (153.6 KB).
//  - Full-layer phases (10 kt, 100 MFMA/wave) -> 43 phases total instead of
//    76 (barrier/serial overhead amortized 2x).
//  - Layer-phase compute touches NO vmem -> staging (2 half-slots/phase,
//    issued 2 phases ahead) floats behind compute; end-of-phase
//    s_waitcnt vmcnt(12) uses the MIN per-wave issue count (waves 1-3 issue
//    12/pair, wave 0 issues 14) fixing r10's per-wave-count hole.
//  - acc[2][5] f32x16 accumulators (AGPR), resid[2][5] f32 in VGPR;
//    weight-k-order permutation in prep (unchanged) keeps the layer-to-layer
//    handoff lane-local: 8 v_cvt_pk_bf16_f32 per kt.
// ============================================================================

typedef __attribute__((ext_vector_type(8))) short bfrag8;     // 8 x bf16
typedef __attribute__((ext_vector_type(16))) float f32x16;    // MFMA 32x32 acc
typedef __attribute__((ext_vector_type(4))) uint32_t u32x4;

#define MFMA32(a, b, c) __builtin_amdgcn_mfma_f32_32x32x16_bf16((a), (b), (c), 0, 0, 0)

#define NFRAG_TOTAL 1855   // 245 embed + 32*50 layer + 10 head 1KB frag-blocks
#define SLOT_BYTES  25600
#define SLOT_ELEMS  12800

#define WAITVM(N) asm volatile("s_waitcnt vmcnt(" #N ")" ::: "memory")

static __device__ __forceinline__ uint16_t f2bf16u(float v) {
    uint32_t u = __builtin_bit_cast(uint32_t, v);
    uint32_t r = u + 0x7FFFu + ((u >> 16) & 1u);
    return (uint16_t)(r >> 16);
}
static __device__ __forceinline__ uint32_t pack2_bf16(float lo, float hi) {
    return (uint32_t)f2bf16u(lo) | ((uint32_t)f2bf16u(hi) << 16);
}
static __device__ __forceinline__ uint32_t cvtpk(float lo, float hi) {
    uint32_t r;
    asm("v_cvt_pk_bf16_f32 %0, %1, %2" : "=v"(r) : "v"(lo), "v"(hi));
    return r;
}
// async global->LDS, 16B per lane; lds dest = wave-uniform base + lane*16
static __device__ __forceinline__ void gl_lds16(const void* g, void* l) {
    __builtin_amdgcn_global_load_lds(
        (const __attribute__((address_space(1))) uint32_t*)g,
        (__attribute__((address_space(3))) uint32_t*)l, 16, 0, 0);
}

// ---------------------------------------------------------------------------
// prep: build 1KB A-fragment blocks (W^T as MFMA A operand, bf16). Unchanged
// from r9/r10 (verified): layer/head k-order permuted so resid regs pack
// directly into the next layer's B fragment.
// ---------------------------------------------------------------------------
__global__ __launch_bounds__(256) void resmlp_prep(
    const float* __restrict__ embed_w, const float* __restrict__ layer_w,
    const float* __restrict__ head_w, uint16_t* __restrict__ ws)
{
    const int fb = blockIdx.x * 4 + (threadIdx.x >> 6);
    if (fb >= NFRAG_TOTAL) return;
    const int l = threadIdx.x & 63;
    const int h = l >> 5, m32 = l & 31;
    float v[8];
    if (fb < 245) {
        const int kt = fb / 5, mt = fb % 5;
        const int m = mt * 32 + m32;
        const int kb = kt * 16 + h * 8;
#pragma unroll
        for (int j = 0; j < 8; ++j)
            v[j] = embed_w[(size_t)(kb + j) * 160 + m];
    } else if (fb < 1845) {
        const int t = fb - 245, L = t / 50, r = t % 50, kt = r / 5, mt = r % 5;
        const int m = mt * 32 + m32;
        const float* W = layer_w + (size_t)L * 25600;
        const int kb = 32 * (kt >> 1) + 16 * (kt & 1) + 4 * h;
#pragma unroll
        for (int j = 0; j < 8; ++j)
            v[j] = W[(size_t)(kb + (j & 3) + 8 * (j >> 2)) * 160 + m];
    } else {
        const int kt = fb - 1845;
        const int kb = 32 * (kt >> 1) + 16 * (kt & 1) + 4 * h;
#pragma unroll
        for (int j = 0; j < 8; ++j)
            v[j] = (m32 < 10) ? head_w[(kb + (j & 3) + 8 * (j >> 2)) * 10 + m32] : 0.f;
    }
    u32x4 wv;
    wv.x = pack2_bf16(v[0], v[1]);
    wv.y = pack2_bf16(v[2], v[3]);
    wv.z = pack2_bf16(v[4], v[5]);
    wv.w = pack2_bf16(v[6], v[7]);
    *(u32x4*)((char*)ws + (size_t)fb * 1024 + l * 16) = wv;
}

// ---------------------------------------------------------------------------
// embed half-unit: 5 kt (or 4 for e=9), 5 mt, 2 batch sets, x JIT from HBM.
// ---------------------------------------------------------------------------
template<int NKT>
static __device__ __forceinline__ void embed_half(
    const uint16_t* __restrict__ buf,
    const float* __restrict__ xr0, const float* __restrict__ xr1,
    int kb, f32x16 (&acc)[2][5], int lane8)
{
#pragma unroll
    for (int kt = 0; kt < NKT; ++kt) {
        const float4 a0 = *(const float4*)(xr0 + kb + kt * 16);
        const float4 a1 = *(const float4*)(xr0 + kb + kt * 16 + 4);
        const float4 c0 = *(const float4*)(xr1 + kb + kt * 16);
        const float4 c1 = *(const float4*)(xr1 + kb + kt * 16 + 4);
        u32x4 w0, w1;
        w0.x = cvtpk(a0.x, a0.y); w0.y = cvtpk(a0.z, a0.w);
        w0.z = cvtpk(a1.x, a1.y); w0.w = cvtpk(a1.z, a1.w);
        w1.x = cvtpk(c0.x, c0.y); w1.y = cvtpk(c0.z, c0.w);
        w1.z = cvtpk(c1.x, c1.y); w1.w = cvtpk(c1.z, c1.w);
        const bfrag8 b0 = __builtin_bit_cast(bfrag8, w0);
        const bfrag8 b1 = __builtin_bit_cast(bfrag8, w1);
#pragma unroll
        for (int mt = 0; mt < 5; ++mt) {
            const bfrag8 a = *(const bfrag8*)(buf + (kt * 5 + mt) * 512 + lane8);
            acc[0][mt] = MFMA32(a, b0, acc[0][mt]);
            acc[1][mt] = MFMA32(a, b1, acc[1][mt]);
        }
    }
}

// layer/head half-unit: kt = KTB..KTB+4 global; NMT m-tiles; ZC: first kt
// writes acc with a zero C operand (no pre-zero pass).
template<int KTB, int NMT, bool ZC>
static __device__ __forceinline__ void layer_half(
    const uint16_t* __restrict__ buf, f32x16 (&acc)[2][5],
    const f32x16 (&resid)[2][5], const f32x16& zf, int lane8)
{
#pragma unroll
    for (int i = 0; i < 5; ++i) {
        const int kt = KTB + i, ms = kt >> 1, rb = (kt & 1) * 8;
        u32x4 w0, w1;
        w0.x = cvtpk(resid[0][ms][rb + 0], resid[0][ms][rb + 1]);
        w0.y = cvtpk(resid[0][ms][rb + 2], resid[0][ms][rb + 3]);
        w0.z = cvtpk(resid[0][ms][rb + 4], resid[0][ms][rb + 5]);
        w0.w = cvtpk(resid[0][ms][rb + 6], resid[0][ms][rb + 7]);
        w1.x = cvtpk(resid[1][ms][rb + 0], resid[1][ms][rb + 1]);
        w1.y = cvtpk(resid[1][ms][rb + 2], resid[1][ms][rb + 3]);
        w1.z = cvtpk(resid[1][ms][rb + 4], resid[1][ms][rb + 5]);
        w1.w = cvtpk(resid[1][ms][rb + 6], resid[1][ms][rb + 7]);
        const bfrag8 b0 = __builtin_bit_cast(bfrag8, w0);
        const bfrag8 b1 = __builtin_bit_cast(bfrag8, w1);
#pragma unroll
        for (int mt = 0; mt < NMT; ++mt) {
            const bfrag8 a = *(const bfrag8*)(buf + (i * NMT + mt) * 512 + lane8);
            if (ZC && i == 0) {
                acc[0][mt] = MFMA32(a, b0, zf);
                acc[1][mt] = MFMA32(a, b1, zf);
            } else {
                acc[0][mt] = MFMA32(a, b0, acc[0][mt]);
                acc[1][mt] = MFMA32(a, b1, acc[1][mt]);
            }
        }
    }
}

// ---------------------------------------------------------------------------
__global__ __launch_bounds__(256, 1) void resmlp_main(
    const float* __restrict__ x,
    const float* __restrict__ embed_b,
    const float* __restrict__ head_b,
    const uint16_t* __restrict__ ws,
    float* __restrict__ out)
{
    extern __shared__ __align__(16) uint16_t lds[];   // 6 x 25600 B ring
    const int tid  = threadIdx.x;
    const int wave = tid >> 6, lane = tid & 63;
    const int hi = lane >> 5, ln = lane & 31;
    const int lane8 = lane * 8;                       // u16 elems = lane*16 B
    const int batch0 = blockIdx.x * 256 + wave * 64;
    const float* xr0 = x + (size_t)(batch0 + ln) * 784 + hi * 8;
    const float* xr1 = xr0 + (size_t)32 * 784;

    f32x16 acc[2][5], resid[2][5];
#pragma unroll
    for (int s = 0; s < 2; ++s)
#pragma unroll
        for (int mt = 0; mt < 5; ++mt)
#pragma unroll
            for (int r = 0; r < 16; ++r) acc[s][mt][r] = 0.f;
    f32x16 zf;
#pragma unroll
    for (int r = 0; r < 16; ++r) zf[r] = 0.f;

    // stage half-unit u (0..75) into ring slot `slot`
    auto do_stage = [&](int u, int slot) {
        int S, C;
        if (u < 10)      { S = (u >> 1) * 50 + (u & 1) * 25; C = (u == 9) ? 20 : 25; }
        else if (u < 74) { S = 245 + (u - 10) * 25;          C = 25; }
        else             { S = 1845 + (u - 74) * 5;          C = 5;  }
        const char* src = (const char*)ws + (size_t)S * 1024 + lane * 16;
        char* dst = (char*)lds + (size_t)slot * SLOT_BYTES + lane * 16;
        for (int i = wave; i < C; i += 4)
            gl_lds16(src + (size_t)i * 1024, dst + i * 1024);
    };

    // ---- prologue ----
    do_stage(0, 0);
    WAITVM(0);
    __builtin_amdgcn_s_barrier();

    // ---- embed half-phases e=0..7 (depth-1 staging; x JIT loads force the
    //      in-flight stage to drain mid-phase, which is fine here) ----
    for (int e = 0; e < 8; ++e) {
        do_stage(e + 1, (e + 1) % 6);
        embed_half<5>(lds + (e % 6) * SLOT_ELEMS, xr0, xr1, e * 80, acc, lane8);
        WAITVM(0);
        __builtin_amdgcn_s_barrier();
    }
    // e=8: also pre-warm layer halves 10,11 (issued AFTER compute so the x
    // consumption waits don't drain them)
    do_stage(9, 3);
    embed_half<5>(lds + 2 * SLOT_ELEMS, xr0, xr1, 640, acc, lane8);
    do_stage(10, 4);
    do_stage(11, 5);
    WAITVM(12);                     // half 9 landed (10,11 = min 12 newest)
    __builtin_amdgcn_s_barrier();
    // e=9 (4 kt tail)
    embed_half<4>(lds + 3 * SLOT_ELEMS, xr0, xr1, 720, acc, lane8);
    do_stage(12, 0);
    do_stage(13, 1);
    WAITVM(12);                     // halves 10,11 landed
    __builtin_amdgcn_s_barrier();

    // ---- 32 residual layers: full-layer phases, staging 2 phases ahead ----
    int sA = 4, sS = 2, hS = 14;
    for (int L = 0; L < 32; ++L) {
        if (L <= 30) {              // L=30 stages head halves 74,75 (C=5)
            do_stage(hS, sS);
            do_stage(hS + 1, sS + 1);
        }
        // boundary VALU: resid update (overlaps in-flight staging)
        if (L == 0) {
#pragma unroll
            for (int s = 0; s < 2; ++s)
#pragma unroll
                for (int mt = 0; mt < 5; ++mt)
#pragma unroll
                    for (int q2 = 0; q2 < 4; ++q2) {
                        const float4 b4 = *(const float4*)(embed_b + mt * 32 + q2 * 8 + hi * 4);
                        resid[s][mt][q2 * 4 + 0] = acc[s][mt][q2 * 4 + 0] + b4.x;
                        resid[s][mt][q2 * 4 + 1] = acc[s][mt][q2 * 4 + 1] + b4.y;
                        resid[s][mt][q2 * 4 + 2] = acc[s][mt][q2 * 4 + 2] + b4.z;
                        resid[s][mt][q2 * 4 + 3] = acc[s][mt][q2 * 4 + 3] + b4.w;
                    }
        } else {
#pragma unroll
            for (int s = 0; s < 2; ++s)
#pragma unroll
                for (int mt = 0; mt < 5; ++mt)
#pragma unroll
                    for (int r = 0; r < 16; ++r)
                        resid[s][mt][r] += fmaxf(acc[s][mt][r], 0.f);
        }
        // compute: pure LDS+MFMA, no vmem -> staging floats behind it
        layer_half<0, 5, true >(lds + sA * SLOT_ELEMS, acc, resid, zf, lane8);
        layer_half<5, 5, false>(lds + (sA + 1) * SLOT_ELEMS, acc, resid, zf, lane8);
        // end-of-phase: ensure the pair consumed NEXT phase has landed for
        // EVERY wave (min per-wave issues this phase: 12 layer / 2 head)
        if (L <= 29)      { WAITVM(12); }
        else if (L == 30) { WAITVM(2);  }
        else              { WAITVM(0);  }
        __builtin_amdgcn_s_barrier();
        sA += 2; if (sA >= 6) sA -= 6;
        sS += 2; if (sS >= 6) sS -= 6;
        hS += 2;
    }

    // ---- head: halves 74,75 in slots 2,3 ----
#pragma unroll
    for (int s = 0; s < 2; ++s)
#pragma unroll
        for (int mt = 0; mt < 5; ++mt)
#pragma unroll
            for (int r = 0; r < 16; ++r)
                resid[s][mt][r] += fmaxf(acc[s][mt][r], 0.f);
    layer_half<0, 1, true >(lds + 2 * SLOT_ELEMS, acc, resid, zf, lane8);
    layer_half<5, 1, false>(lds + 3 * SLOT_ELEMS, acc, resid, zf, lane8);

    // epilogue: D row h' = (r&3)+8*(r>>2)+4*hi -> class (h'<10), 2 batch sets
#pragma unroll
    for (int s = 0; s < 2; ++s) {
        float* op = out + (size_t)(batch0 + s * 32 + ln) * 10;
        const f32x16 a = acc[s][0];
        if (hi == 0) {
            op[0] = a[0] + head_b[0];
            op[1] = a[1] + head_b[1];
            op[2] = a[2] + head_b[2];
            op[3] = a[3] + head_b[3];
            op[8] = a[4] + head_b[8];
            op[9] = a[5] + head_b[9];
        } else {
            op[4] = a[0] + head_b[4];
            op[5] = a[1] + head_b[5];
            op[6] = a[2] + head_b[6];
            op[7] = a[3] + head_b[7];
        }
    }
}

// ---------------------------------------------------------------------------
extern "C" void kernel_launch(void* const* d_in, const int* in_sizes, int n_in,
                              void* d_out, int out_size, void* d_ws, size_t ws_size,
                              hipStream_t stream) {
    (void)in_sizes; (void)n_in; (void)out_size; (void)ws_size;
    const float* x       = (const float*)d_in[0];
    const float* embed_w = (const float*)d_in[1];
    const float* embed_b = (const float*)d_in[2];
    const float* layer_w = (const float*)d_in[3];
    const float* head_w  = (const float*)d_in[4];
    const float* head_b  = (const float*)d_in[5];
    float* out = (float*)d_out;

    uint16_t* ws = (uint16_t*)d_ws;   // 1855 KB of frag-blocks

    const int dynLds = 6 * SLOT_BYTES;   // 153600 B -> 1 block/CU
    (void)hipFuncSetAttribute((const void*)resmlp_main,
                              hipFuncAttributeMaxDynamicSharedMemorySize, dynLds);

    resmlp_prep<<<(NFRAG_TOTAL + 3) / 4, 256, 0, stream>>>(embed_w, layer_w, head_w, ws);
    resmlp_main<<<256, 256, dynLds, stream>>>(x, embed_b, head_b, ws, out);
}

// Round 4
// 506.725 us; speedup vs baseline: 1.2128x; 1.2128x over previous
//
#include <hip/hip_runtime.h>
#include <cstdint>
#include <cstddef>

// ============================================================================
// ResMLP fused kernels for MI355X (gfx950) — round 12
//
// Three kernels:
//  1. prep  : weights -> 1KB LDS-ready A-frag blocks (unchanged, verified).
//  2. embed : x @ We + b  -> H (bf16, column-PERMUTED to the MFMA D layout).
//             2 blocks/CU, 8 waves of 32 rows — good occupancy for the
//             x-HBM-bound regime.
//  3. main  : 32 layers + head, 64 batch rows PER WAVE (one weight ds_read
//             feeds TWO MFMAs -> LDS traffic per FLOP halved), 1 block/CU.
//
// r11's spill (VGPR=256, 250MB scratch) fixed by:
//  - resid as SCALAR float[2][5][16] (no 16-wide tuple alignment pressure)
//  - accumulators FORCED into AGPRs via inline-asm MFMA ("+a"/"=a")
//  - sched_barrier(0) after resid update (stops acc live-range doubling)
// r11's cross-wave staging race fixed: each wave waits for its OWN copy of
// the NEXT phase's units before the phase-end barrier; the barrier then
// publishes "units <= 2L+1 landed in LDS" to all waves.
// ============================================================================

typedef __attribute__((ext_vector_type(8))) short bfrag8;     // 8 x bf16
typedef __attribute__((ext_vector_type(16))) float f32x16;    // MFMA 32x32 acc
typedef __attribute__((ext_vector_type(4))) uint32_t u32x4;

#define NFRAG_TOTAL 1855   // 245 embed + 32*50 layer + 10 head 1KB frag-blocks
#define SLOT_BYTES  25600
#define SLOT_ELEMS  12800
#define H_OFFSET    1899520   // bytes: 1855*1024, start of H in ws

#define WAITVM(N) asm volatile("s_waitcnt vmcnt(" #N ")" ::: "memory")

static __device__ __forceinline__ uint16_t f2bf16u(float v) {
    uint32_t u = __builtin_bit_cast(uint32_t, v);
    uint32_t r = u + 0x7FFFu + ((u >> 16) & 1u);
    return (uint16_t)(r >> 16);
}
static __device__ __forceinline__ uint32_t pack2_bf16(float lo, float hi) {
    return (uint32_t)f2bf16u(lo) | ((uint32_t)f2bf16u(hi) << 16);
}
static __device__ __forceinline__ uint32_t cvtpk(float lo, float hi) {
    uint32_t r;
    asm("v_cvt_pk_bf16_f32 %0, %1, %2" : "=v"(r) : "v"(lo), "v"(hi));
    return r;
}
// async global->LDS, 16B per lane; lds dest = wave-uniform base + lane*16
static __device__ __forceinline__ void gl_lds16(const void* g, void* l) {
    __builtin_amdgcn_global_load_lds(
        (const __attribute__((address_space(1))) uint32_t*)g,
        (__attribute__((address_space(3))) uint32_t*)l, 16, 0, 0);
}
// MFMA with accumulator pinned to AGPRs
static __device__ __forceinline__ void mfma_acc(f32x16& c, bfrag8 a, bfrag8 b) {
    asm("v_mfma_f32_32x32x16_bf16 %0, %1, %2, %0" : "+a"(c) : "v"(a), "v"(b));
}
static __device__ __forceinline__ f32x16 mfma_zc(bfrag8 a, bfrag8 b, f32x16 za) {
    f32x16 d;
    asm("v_mfma_f32_32x32x16_bf16 %0, %1, %2, %3"
        : "=a"(d) : "v"(a), "v"(b), "a"(za));
    return d;
}
template<int RB>
static __device__ __forceinline__ bfrag8 bprep(const float (&r)[16]) {
    u32x4 w;
    w.x = cvtpk(r[RB + 0], r[RB + 1]);
    w.y = cvtpk(r[RB + 2], r[RB + 3]);
    w.z = cvtpk(r[RB + 4], r[RB + 5]);
    w.w = cvtpk(r[RB + 6], r[RB + 7]);
    return __builtin_bit_cast(bfrag8, w);
}

// ---------------------------------------------------------------------------
// prep: build 1KB A-fragment blocks (W^T as MFMA A operand, bf16). Verified.
//   embed  (fb<245):   kt=fb/5, mt=fb%5,  k natural = kt*16 + h*8 + j
//   layer  (fb<1845):  k permuted: khid = 32*(kt>>1)+16*(kt&1)+4h+(j&3)+8*(j>>2)
//   head   (else):     same permuted k; m>=10 zero-padded
// ---------------------------------------------------------------------------
__global__ __launch_bounds__(256) void resmlp_prep(
    const float* __restrict__ embed_w, const float* __restrict__ layer_w,
    const float* __restrict__ head_w, uint16_t* __restrict__ ws)
{
    const int fb = blockIdx.x * 4 + (threadIdx.x >> 6);
    if (fb >= NFRAG_TOTAL) return;
    const int l = threadIdx.x & 63;
    const int h = l >> 5, m32 = l & 31;
    float v[8];
    if (fb < 245) {
        const int kt = fb / 5, mt = fb % 5;
        const int m = mt * 32 + m32;
        const int kb = kt * 16 + h * 8;
#pragma unroll
        for (int j = 0; j < 8; ++j)
            v[j] = embed_w[(size_t)(kb + j) * 160 + m];
    } else if (fb < 1845) {
        const int t = fb - 245, L = t / 50, r = t % 50, kt = r / 5, mt = r % 5;
        const int m = mt * 32 + m32;
        const float* W = layer_w + (size_t)L * 25600;
        const int kb = 32 * (kt >> 1) + 16 * (kt & 1) + 4 * h;
#pragma unroll
        for (int j = 0; j < 8; ++j)
            v[j] = W[(size_t)(kb + (j & 3) + 8 * (j >> 2)) * 160 + m];
    } else {
        const int kt = fb - 1845;
        const int kb = 32 * (kt >> 1) + 16 * (kt & 1) + 4 * h;
#pragma unroll
        for (int j = 0; j < 8; ++j)
            v[j] = (m32 < 10) ? head_w[(kb + (j & 3) + 8 * (j >> 2)) * 10 + m32] : 0.f;
    }
    u32x4 wv;
    wv.x = pack2_bf16(v[0], v[1]);
    wv.y = pack2_bf16(v[2], v[3]);
    wv.z = pack2_bf16(v[4], v[5]);
    wv.w = pack2_bf16(v[6], v[7]);
    *(u32x4*)((char*)ws + (size_t)fb * 1024 + l * 16) = wv;
}

// ---------------------------------------------------------------------------
// embed: h0 = x @ We + b, written to H as bf16 in the PERMUTED column layout
//   H[row][mt*32 + hi*16 + r] = h0[row][mt*32 + (r&3) + 8*(r>>2) + 4*hi]
// grid 512 x 256thr (2 blocks/CU), 32 rows/wave, 3-slot LDS ring.
// ---------------------------------------------------------------------------
__global__ __launch_bounds__(256, 2) void resmlp_embed(
    const float* __restrict__ x, const float* __restrict__ embed_b,
    const uint16_t* __restrict__ ws, uint16_t* __restrict__ H)
{
    extern __shared__ __align__(16) uint16_t lds[];   // 3 x 25600 B
    const int tid = threadIdx.x;
    const int wave = tid >> 6, lane = tid & 63;
    const int hi = lane >> 5, ln = lane & 31;
    const int lane8 = lane * 8;
    const int row = blockIdx.x * 128 + wave * 32 + ln;
    const float* xb = x + (size_t)row * 784 + hi * 8;

    f32x16 acc[5];
#pragma unroll
    for (int mt = 0; mt < 5; ++mt)
#pragma unroll
        for (int r = 0; r < 16; ++r) acc[mt][r] = 0.f;

    auto do_stage = [&](int e) {
        const int S = e * 25, C = (e == 9) ? 20 : 25;
        const char* src = (const char*)ws + (size_t)S * 1024 + lane * 16;
        char* dst = (char*)lds + (e % 3) * SLOT_BYTES + lane * 16;
        for (int i = wave; i < C; i += 4)
            gl_lds16(src + (size_t)i * 1024, dst + i * 1024);
    };

    do_stage(0);
    do_stage(1);
    WAITVM(6);                       // own unit-0 loads landed (w1-3 min)
    __builtin_amdgcn_s_barrier();

    for (int e = 0; e < 9; ++e) {
        // x loads FIRST (oldest in vmem FIFO so their consumption doesn't
        // drain the freshly issued stage of unit e+2)
        float4 xv[10];
#pragma unroll
        for (int kt = 0; kt < 5; ++kt) {
            xv[2 * kt]     = *(const float4*)(xb + e * 80 + kt * 16);
            xv[2 * kt + 1] = *(const float4*)(xb + e * 80 + kt * 16 + 4);
        }
        if (e <= 7) do_stage(e + 2);
        const uint16_t* buf = lds + (e % 3) * SLOT_ELEMS;
#pragma unroll
        for (int kt = 0; kt < 5; ++kt) {
            u32x4 w;
            w.x = cvtpk(xv[2 * kt].x, xv[2 * kt].y);
            w.y = cvtpk(xv[2 * kt].z, xv[2 * kt].w);
            w.z = cvtpk(xv[2 * kt + 1].x, xv[2 * kt + 1].y);
            w.w = cvtpk(xv[2 * kt + 1].z, xv[2 * kt + 1].w);
            const bfrag8 b = __builtin_bit_cast(bfrag8, w);
#pragma unroll
            for (int mt = 0; mt < 5; ++mt)
                mfma_acc(acc[mt], *(const bfrag8*)(buf + (kt * 5 + mt) * 512 + lane8), b);
        }
        if (e <= 7) { WAITVM(6); } else { WAITVM(0); }  // own unit e+1 landed
        __builtin_amdgcn_s_barrier();
    }
    // e = 9 tail: 4 kt (k 720..783)
    {
        const uint16_t* buf = lds + 0 * SLOT_ELEMS;     // 9 % 3
#pragma unroll
        for (int kt = 0; kt < 4; ++kt) {
            const float4 v0 = *(const float4*)(xb + 720 + kt * 16);
            const float4 v1 = *(const float4*)(xb + 720 + kt * 16 + 4);
            u32x4 w;
            w.x = cvtpk(v0.x, v0.y); w.y = cvtpk(v0.z, v0.w);
            w.z = cvtpk(v1.x, v1.y); w.w = cvtpk(v1.z, v1.w);
            const bfrag8 b = __builtin_bit_cast(bfrag8, w);
#pragma unroll
            for (int mt = 0; mt < 5; ++mt)
                mfma_acc(acc[mt], *(const bfrag8*)(buf + (kt * 5 + mt) * 512 + lane8), b);
        }
    }

    asm volatile("s_nop 7\n\ts_nop 7\n\ts_nop 7" ::: );  // MFMA->VALU hazard gap
    // epilogue: + bias, pack bf16, store 32B per mt (permuted layout)
    uint16_t* hb = H + (size_t)row * 160;
#pragma unroll
    for (int mt = 0; mt < 5; ++mt) {
        float v[16];
#pragma unroll
        for (int q2 = 0; q2 < 4; ++q2) {
            const float4 b4 = *(const float4*)(embed_b + mt * 32 + q2 * 8 + hi * 4);
            v[q2 * 4 + 0] = acc[mt][q2 * 4 + 0] + b4.x;
            v[q2 * 4 + 1] = acc[mt][q2 * 4 + 1] + b4.y;
            v[q2 * 4 + 2] = acc[mt][q2 * 4 + 2] + b4.z;
            v[q2 * 4 + 3] = acc[mt][q2 * 4 + 3] + b4.w;
        }
        u32x4 o0, o1;
        o0.x = pack2_bf16(v[0], v[1]);   o0.y = pack2_bf16(v[2], v[3]);
        o0.z = pack2_bf16(v[4], v[5]);   o0.w = pack2_bf16(v[6], v[7]);
        o1.x = pack2_bf16(v[8], v[9]);   o1.y = pack2_bf16(v[10], v[11]);
        o1.z = pack2_bf16(v[12], v[13]); o1.w = pack2_bf16(v[14], v[15]);
        *(u32x4*)(hb + mt * 32 + hi * 16)     = o0;
        *(u32x4*)(hb + mt * 32 + hi * 16 + 8) = o1;
    }
}

// ---------------------------------------------------------------------------
// main: one full layer (10 kt) over two half-slots, 64 rows/wave (2 b-sets),
// explicit 1-group-lookahead A-frag register pipeline.
// ---------------------------------------------------------------------------
template<int NMT>
static __device__ __forceinline__ void layer10(
    const uint16_t* __restrict__ bufA, const uint16_t* __restrict__ bufB,
    f32x16 (&acc)[2][5], const float (&resid)[2][5][16],
    f32x16 za, int lane8)
{
    bfrag8 fe[NMT], fo[NMT];
#pragma unroll
    for (int mt = 0; mt < NMT; ++mt)
        fe[mt] = *(const bfrag8*)(bufA + mt * 512 + lane8);
#pragma unroll
    for (int kp = 0; kp < 5; ++kp) {
        {   // prefetch odd kt = 2kp+1
            const uint16_t* nb = (2 * kp + 1 < 5) ? bufA : bufB;
            const int kl = (2 * kp + 1) % 5;
#pragma unroll
            for (int mt = 0; mt < NMT; ++mt)
                fo[mt] = *(const bfrag8*)(nb + (kl * NMT + mt) * 512 + lane8);
        }
        {   // compute even kt = 2kp  (ms = kp, rb = 0)
            const bfrag8 b0 = bprep<0>(resid[0][kp]);
            const bfrag8 b1 = bprep<0>(resid[1][kp]);
#pragma unroll
            for (int mt = 0; mt < NMT; ++mt) {
                if (kp == 0) {
                    acc[0][mt] = mfma_zc(fe[mt], b0, za);
                    acc[1][mt] = mfma_zc(fe[mt], b1, za);
                } else {
                    mfma_acc(acc[0][mt], fe[mt], b0);
                    mfma_acc(acc[1][mt], fe[mt], b1);
                }
            }
        }
        if (kp < 4) {   // prefetch next even kt = 2kp+2
            const uint16_t* nb = (2 * kp + 2 < 5) ? bufA : bufB;
            const int kl = (2 * kp + 2) % 5;
#pragma unroll
            for (int mt = 0; mt < NMT; ++mt)
                fe[mt] = *(const bfrag8*)(nb + (kl * NMT + mt) * 512 + lane8);
        }
        {   // compute odd kt = 2kp+1 (ms = kp, rb = 8)
            const bfrag8 b0 = bprep<8>(resid[0][kp]);
            const bfrag8 b1 = bprep<8>(resid[1][kp]);
#pragma unroll
            for (int mt = 0; mt < NMT; ++mt) {
                mfma_acc(acc[0][mt], fo[mt], b0);
                mfma_acc(acc[1][mt], fo[mt], b1);
            }
        }
    }
}

__global__ __launch_bounds__(256, 1) void resmlp_main(
    const uint16_t* __restrict__ H,
    const float* __restrict__ head_b,
    const uint16_t* __restrict__ ws,
    float* __restrict__ out)
{
    extern __shared__ __align__(16) uint16_t lds[];   // 6 x 25600 B ring
    const int tid = threadIdx.x;
    const int wave = tid >> 6, lane = tid & 63;
    const int hi = lane >> 5, ln = lane & 31;
    const int lane8 = lane * 8;
    const int batch0 = blockIdx.x * 256 + wave * 64;

    // ---- load resid = h0 from H (before ANY staging: clean vmcnt FIFO) ----
    float resid[2][5][16];
#pragma unroll
    for (int s = 0; s < 2; ++s)
#pragma unroll
        for (int mt = 0; mt < 5; ++mt) {
            const uint16_t* hp = H + (size_t)(batch0 + s * 32 + ln) * 160
                                   + mt * 32 + hi * 16;
            const u32x4 pa = *(const u32x4*)hp;
            const u32x4 pb = *(const u32x4*)(hp + 8);
            const uint32_t u[8] = {pa.x, pa.y, pa.z, pa.w, pb.x, pb.y, pb.z, pb.w};
#pragma unroll
            for (int j = 0; j < 8; ++j) {
                resid[s][mt][2 * j]     = __builtin_bit_cast(float, u[j] << 16);
                resid[s][mt][2 * j + 1] = __builtin_bit_cast(float, u[j] & 0xFFFF0000u);
            }
        }

    f32x16 za;
#pragma unroll
    for (int r = 0; r < 16; ++r) za[r] = 0.f;
    f32x16 acc[2][5];

    // stage unit u (0..63 layer halves, 64..65 head halves) into slot u%6
    auto do_stage = [&](int u) {
        int S, C;
        if (u < 64) { S = 245 + u * 25;        C = 25; }
        else        { S = 1845 + (u - 64) * 5; C = 5;  }
        const char* src = (const char*)ws + (size_t)S * 1024 + lane * 16;
        char* dst = (char*)lds + (u % 6) * SLOT_BYTES + lane * 16;
        for (int i = wave; i < C; i += 4)
            gl_lds16(src + (size_t)i * 1024, dst + i * 1024);
    };

    // ---- prologue: 4 units in flight, wait own 0,1, publish via barrier ----
    do_stage(0); do_stage(1); do_stage(2); do_stage(3);
    WAITVM(12);
    __builtin_amdgcn_s_barrier();

    // ---- 32 layers ----
    for (int L = 0; L < 32; ++L) {
        if (L <= 30) { do_stage(2 * L + 4); do_stage(2 * L + 5); }
        if (L > 0) {
#pragma unroll
            for (int s = 0; s < 2; ++s)
#pragma unroll
                for (int mt = 0; mt < 5; ++mt)
#pragma unroll
                    for (int r = 0; r < 16; ++r)
                        resid[s][mt][r] += fmaxf(acc[s][mt][r], 0.f);
            __builtin_amdgcn_sched_barrier(0);   // acc_old dead before redefine
        }
        const uint16_t* bufA = lds + ((2 * L) % 6) * SLOT_ELEMS;
        const uint16_t* bufB = lds + ((2 * L + 1) % 6) * SLOT_ELEMS;
        layer10<5>(bufA, bufB, acc, resid, za, lane8);
        // wait own copies of NEXT phase's units, then publish
        if (L <= 29)      { WAITVM(12); }
        else if (L == 30) { WAITVM(2);  }
        else              { WAITVM(0);  }
        __builtin_amdgcn_s_barrier();
    }

    // ---- head (units 64,65 in slots 4,5) ----
#pragma unroll
    for (int s = 0; s < 2; ++s)
#pragma unroll
        for (int mt = 0; mt < 5; ++mt)
#pragma unroll
            for (int r = 0; r < 16; ++r)
                resid[s][mt][r] += fmaxf(acc[s][mt][r], 0.f);
    __builtin_amdgcn_sched_barrier(0);
    layer10<1>(lds + 4 * SLOT_ELEMS, lds + 5 * SLOT_ELEMS, acc, resid, za, lane8);

    asm volatile("s_nop 7\n\ts_nop 7\n\ts_nop 7" ::: );  // MFMA->VALU hazard gap
    // epilogue: class = (r&3)+8*(r>>2)+4*hi  (valid classes < 10)
#pragma unroll
    for (int s = 0; s < 2; ++s) {
        float* op = out + (size_t)(batch0 + s * 32 + ln) * 10;
        if (hi == 0) {
            op[0] = acc[s][0][0] + head_b[0];
            op[1] = acc[s][0][1] + head_b[1];
            op[2] = acc[s][0][2] + head_b[2];
            op[3] = acc[s][0][3] + head_b[3];
            op[8] = acc[s][0][4] + head_b[8];
            op[9] = acc[s][0][5] + head_b[9];
        } else {
            op[4] = acc[s][0][0] + head_b[4];
            op[5] = acc[s][0][1] + head_b[5];
            op[6] = acc[s][0][2] + head_b[6];
            op[7] = acc[s][0][3] + head_b[7];
        }
    }
}

// ---------------------------------------------------------------------------
extern "C" void kernel_launch(void* const* d_in, const int* in_sizes, int n_in,
                              void* d_out, int out_size, void* d_ws, size_t ws_size,
                              hipStream_t stream) {
    (void)in_sizes; (void)n_in; (void)out_size; (void)ws_size;
    const float* x       = (const float*)d_in[0];
    const float* embed_w = (const float*)d_in[1];
    const float* embed_b = (const float*)d_in[2];
    const float* layer_w = (const float*)d_in[3];
    const float* head_w  = (const float*)d_in[4];
    const float* head_b  = (const float*)d_in[5];
    float* out = (float*)d_out;

    uint16_t* ws = (uint16_t*)d_ws;                       // frags: 1.86 MB
    uint16_t* H  = (uint16_t*)((char*)d_ws + H_OFFSET);   // h0 bf16: 21 MB

    const int ldsE = 3 * SLOT_BYTES;   // 76800 B  -> 2 blocks/CU
    const int ldsM = 6 * SLOT_BYTES;   // 153600 B -> 1 block/CU
    (void)hipFuncSetAttribute((const void*)resmlp_embed,
                              hipFuncAttributeMaxDynamicSharedMemorySize, ldsE);
    (void)hipFuncSetAttribute((const void*)resmlp_main,
                              hipFuncAttributeMaxDynamicSharedMemorySize, ldsM);

    resmlp_prep<<<(NFRAG_TOTAL + 3) / 4, 256, 0, stream>>>(embed_w, layer_w, head_w, ws);
    resmlp_embed<<<512, 256, ldsE, stream>>>(x, embed_b, ws, H);
    resmlp_main<<<256, 256, ldsM, stream>>>(H, head_b, ws, out);
}

// Round 5
// 443.725 us; speedup vs baseline: 1.3849x; 1.1420x over previous
//
#include <hip/hip_runtime.h>
#include <cstdint>
#include <cstddef>

// ============================================================================
// ResMLP fused kernels for MI355X (gfx950) — round 13
//
// Same structure as r12 (verified correct): prep -> frag blocks; embed ->
// H bf16 in permuted D layout; main = 32 layers + head, 64 rows/wave,
// 1 block/CU, 6-slot LDS ring, own-wait+barrier-publish staging.
//
// r12 post-mortem: inline-asm AGPR pinning generated ~1400 extra VALU
// instrs/wave/layer of AGPR<->VGPR copy churn sitting in the acc dep chain
// (VALUBusy 26% = 2100 instrs/wave/layer vs ~700 expected), and the opaque
// asm blocks blocked scheduling. At 1 wave/SIMD every bubble is a dead SIMD.
//
// r13: builtin MFMA (compiler allocates AGPRs copy-free, inserts exact
// hazard waits, schedules cvt_pk/ds_read into the 32-cyc MFMA shadow),
// resid stays SCALAR float (that was the real r11-spill fix), no
// sched_barrier, no manual s_nop.
// ============================================================================

typedef __attribute__((ext_vector_type(8))) short bfrag8;     // 8 x bf16
typedef __attribute__((ext_vector_type(16))) float f32x16;    // MFMA 32x32 acc
typedef __attribute__((ext_vector_type(4))) uint32_t u32x4;

#define MFMA32(a, b, c) __builtin_amdgcn_mfma_f32_32x32x16_bf16((a), (b), (c), 0, 0, 0)

#define NFRAG_TOTAL 1855   // 245 embed + 32*50 layer + 10 head 1KB frag-blocks
#define SLOT_BYTES  25600
#define SLOT_ELEMS  12800
#define H_OFFSET    1899520   // bytes: 1855*1024, start of H in ws

#define WAITVM(N) asm volatile("s_waitcnt vmcnt(" #N ")" ::: "memory")

static __device__ __forceinline__ uint16_t f2bf16u(float v) {
    uint32_t u = __builtin_bit_cast(uint32_t, v);
    uint32_t r = u + 0x7FFFu + ((u >> 16) & 1u);
    return (uint16_t)(r >> 16);
}
static __device__ __forceinline__ uint32_t pack2_bf16(float lo, float hi) {
    return (uint32_t)f2bf16u(lo) | ((uint32_t)f2bf16u(hi) << 16);
}
static __device__ __forceinline__ uint32_t cvtpk(float lo, float hi) {
    uint32_t r;
    asm("v_cvt_pk_bf16_f32 %0, %1, %2" : "=v"(r) : "v"(lo), "v"(hi));
    return r;
}
// async global->LDS, 16B per lane; lds dest = wave-uniform base + lane*16
static __device__ __forceinline__ void gl_lds16(const void* g, void* l) {
    __builtin_amdgcn_global_load_lds(
        (const __attribute__((address_space(1))) uint32_t*)g,
        (__attribute__((address_space(3))) uint32_t*)l, 16, 0, 0);
}

// ---------------------------------------------------------------------------
// prep: build 1KB A-fragment blocks (W^T as MFMA A operand, bf16). Verified.
//   embed  (fb<245):   kt=fb/5, mt=fb%5,  k natural = kt*16 + h*8 + j
//   layer  (fb<1845):  k permuted: khid = 32*(kt>>1)+16*(kt&1)+4h+(j&3)+8*(j>>2)
//   head   (else):     same permuted k; m>=10 zero-padded
// ---------------------------------------------------------------------------
__global__ __launch_bounds__(256) void resmlp_prep(
    const float* __restrict__ embed_w, const float* __restrict__ layer_w,
    const float* __restrict__ head_w, uint16_t* __restrict__ ws)
{
    const int fb = blockIdx.x * 4 + (threadIdx.x >> 6);
    if (fb >= NFRAG_TOTAL) return;
    const int l = threadIdx.x & 63;
    const int h = l >> 5, m32 = l & 31;
    float v[8];
    if (fb < 245) {
        const int kt = fb / 5, mt = fb % 5;
        const int m = mt * 32 + m32;
        const int kb = kt * 16 + h * 8;
#pragma unroll
        for (int j = 0; j < 8; ++j)
            v[j] = embed_w[(size_t)(kb + j) * 160 + m];
    } else if (fb < 1845) {
        const int t = fb - 245, L = t / 50, r = t % 50, kt = r / 5, mt = r % 5;
        const int m = mt * 32 + m32;
        const float* W = layer_w + (size_t)L * 25600;
        const int kb = 32 * (kt >> 1) + 16 * (kt & 1) + 4 * h;
#pragma unroll
        for (int j = 0; j < 8; ++j)
            v[j] = W[(size_t)(kb + (j & 3) + 8 * (j >> 2)) * 160 + m];
    } else {
        const int kt = fb - 1845;
        const int kb = 32 * (kt >> 1) + 16 * (kt & 1) + 4 * h;
#pragma unroll
        for (int j = 0; j < 8; ++j)
            v[j] = (m32 < 10) ? head_w[(kb + (j & 3) + 8 * (j >> 2)) * 10 + m32] : 0.f;
    }
    u32x4 wv;
    wv.x = pack2_bf16(v[0], v[1]);
    wv.y = pack2_bf16(v[2], v[3]);
    wv.z = pack2_bf16(v[4], v[5]);
    wv.w = pack2_bf16(v[6], v[7]);
    *(u32x4*)((char*)ws + (size_t)fb * 1024 + l * 16) = wv;
}

// ---------------------------------------------------------------------------
// embed: h0 = x @ We + b, written to H as bf16 in the PERMUTED column layout
//   H[row][mt*32 + hi*16 + r] = h0[row][mt*32 + (r&3) + 8*(r>>2) + 4*hi]
// grid 512 x 256thr (2 blocks/CU), 32 rows/wave, 3-slot LDS ring.
// ---------------------------------------------------------------------------
__global__ __launch_bounds__(256, 2) void resmlp_embed(
    const float* __restrict__ x, const float* __restrict__ embed_b,
    const uint16_t* __restrict__ ws, uint16_t* __restrict__ H)
{
    extern __shared__ __align__(16) uint16_t lds[];   // 3 x 25600 B
    const int tid = threadIdx.x;
    const int wave = tid >> 6, lane = tid & 63;
    const int hi = lane >> 5, ln = lane & 31;
    const int lane8 = lane * 8;
    const int row = blockIdx.x * 128 + wave * 32 + ln;
    const float* xb = x + (size_t)row * 784 + hi * 8;

    f32x16 acc[5];
#pragma unroll
    for (int mt = 0; mt < 5; ++mt)
#pragma unroll
        for (int r = 0; r < 16; ++r) acc[mt][r] = 0.f;

    auto do_stage = [&](int e) {
        const int S = e * 25, C = (e == 9) ? 20 : 25;
        const char* src = (const char*)ws + (size_t)S * 1024 + lane * 16;
        char* dst = (char*)lds + (e % 3) * SLOT_BYTES + lane * 16;
        for (int i = wave; i < C; i += 4)
            gl_lds16(src + (size_t)i * 1024, dst + i * 1024);
    };

    do_stage(0);
    do_stage(1);
    WAITVM(6);                       // own unit-0 loads landed (w1-3 min)
    __builtin_amdgcn_s_barrier();

    for (int e = 0; e < 9; ++e) {
        // x loads FIRST (oldest in vmem FIFO so their consumption doesn't
        // drain the freshly issued stage of unit e+2)
        float4 xv[10];
#pragma unroll
        for (int kt = 0; kt < 5; ++kt) {
            xv[2 * kt]     = *(const float4*)(xb + e * 80 + kt * 16);
            xv[2 * kt + 1] = *(const float4*)(xb + e * 80 + kt * 16 + 4);
        }
        if (e <= 7) do_stage(e + 2);
        const uint16_t* buf = lds + (e % 3) * SLOT_ELEMS;
#pragma unroll
        for (int kt = 0; kt < 5; ++kt) {
            u32x4 w;
            w.x = cvtpk(xv[2 * kt].x, xv[2 * kt].y);
            w.y = cvtpk(xv[2 * kt].z, xv[2 * kt].w);
            w.z = cvtpk(xv[2 * kt + 1].x, xv[2 * kt + 1].y);
            w.w = cvtpk(xv[2 * kt + 1].z, xv[2 * kt + 1].w);
            const bfrag8 b = __builtin_bit_cast(bfrag8, w);
#pragma unroll
            for (int mt = 0; mt < 5; ++mt) {
                const bfrag8 a = *(const bfrag8*)(buf + (kt * 5 + mt) * 512 + lane8);
                acc[mt] = MFMA32(a, b, acc[mt]);
            }
        }
        if (e <= 7) { WAITVM(6); } else { WAITVM(0); }  // own unit e+1 landed
        __builtin_amdgcn_s_barrier();
    }
    // e = 9 tail: 4 kt (k 720..783)
    {
        const uint16_t* buf = lds + 0 * SLOT_ELEMS;     // 9 % 3
#pragma unroll
        for (int kt = 0; kt < 4; ++kt) {
            const float4 v0 = *(const float4*)(xb + 720 + kt * 16);
            const float4 v1 = *(const float4*)(xb + 720 + kt * 16 + 4);
            u32x4 w;
            w.x = cvtpk(v0.x, v0.y); w.y = cvtpk(v0.z, v0.w);
            w.z = cvtpk(v1.x, v1.y); w.w = cvtpk(v1.z, v1.w);
            const bfrag8 b = __builtin_bit_cast(bfrag8, w);
#pragma unroll
            for (int mt = 0; mt < 5; ++mt) {
                const bfrag8 a = *(const bfrag8*)(buf + (kt * 5 + mt) * 512 + lane8);
                acc[mt] = MFMA32(a, b, acc[mt]);
            }
        }
    }

    // epilogue: + bias, pack bf16, store 32B per mt (permuted layout)
    uint16_t* hb = H + (size_t)row * 160;
#pragma unroll
    for (int mt = 0; mt < 5; ++mt) {
        float v[16];
#pragma unroll
        for (int q2 = 0; q2 < 4; ++q2) {
            const float4 b4 = *(const float4*)(embed_b + mt * 32 + q2 * 8 + hi * 4);
            v[q2 * 4 + 0] = acc[mt][q2 * 4 + 0] + b4.x;
            v[q2 * 4 + 1] = acc[mt][q2 * 4 + 1] + b4.y;
            v[q2 * 4 + 2] = acc[mt][q2 * 4 + 2] + b4.z;
            v[q2 * 4 + 3] = acc[mt][q2 * 4 + 3] + b4.w;
        }
        u32x4 o0, o1;
        o0.x = pack2_bf16(v[0], v[1]);   o0.y = pack2_bf16(v[2], v[3]);
        o0.z = pack2_bf16(v[4], v[5]);   o0.w = pack2_bf16(v[6], v[7]);
        o1.x = pack2_bf16(v[8], v[9]);   o1.y = pack2_bf16(v[10], v[11]);
        o1.z = pack2_bf16(v[12], v[13]); o1.w = pack2_bf16(v[14], v[15]);
        *(u32x4*)(hb + mt * 32 + hi * 16)     = o0;
        *(u32x4*)(hb + mt * 32 + hi * 16 + 8) = o1;
    }
}

// ---------------------------------------------------------------------------
// main: one full layer (10 kt) over two half-slots, 64 rows/wave (2 b-sets).
// Builtin MFMA; fully-unrolled loops keep every resid index compile-time.
// ---------------------------------------------------------------------------
template<int NMT>
static __device__ __forceinline__ void layer10(
    const uint16_t* __restrict__ bufA, const uint16_t* __restrict__ bufB,
    f32x16 (&acc)[2][5], const float (&resid)[2][5][16],
    const f32x16& zf, int lane8)
{
#pragma unroll
    for (int kt = 0; kt < 10; ++kt) {
        const uint16_t* buf = (kt < 5) ? bufA : bufB;
        const int kl = (kt < 5) ? kt : kt - 5;
        const int ms = kt >> 1, rb = (kt & 1) * 8;
        u32x4 w0, w1;
        w0.x = cvtpk(resid[0][ms][rb + 0], resid[0][ms][rb + 1]);
        w0.y = cvtpk(resid[0][ms][rb + 2], resid[0][ms][rb + 3]);
        w0.z = cvtpk(resid[0][ms][rb + 4], resid[0][ms][rb + 5]);
        w0.w = cvtpk(resid[0][ms][rb + 6], resid[0][ms][rb + 7]);
        w1.x = cvtpk(resid[1][ms][rb + 0], resid[1][ms][rb + 1]);
        w1.y = cvtpk(resid[1][ms][rb + 2], resid[1][ms][rb + 3]);
        w1.z = cvtpk(resid[1][ms][rb + 4], resid[1][ms][rb + 5]);
        w1.w = cvtpk(resid[1][ms][rb + 6], resid[1][ms][rb + 7]);
        const bfrag8 b0 = __builtin_bit_cast(bfrag8, w0);
        const bfrag8 b1 = __builtin_bit_cast(bfrag8, w1);
#pragma unroll
        for (int mt = 0; mt < NMT; ++mt) {
            const bfrag8 a = *(const bfrag8*)(buf + (kl * NMT + mt) * 512 + lane8);
            if (kt == 0) {
                acc[0][mt] = MFMA32(a, b0, zf);
                acc[1][mt] = MFMA32(a, b1, zf);
            } else {
                acc[0][mt] = MFMA32(a, b0, acc[0][mt]);
                acc[1][mt] = MFMA32(a, b1, acc[1][mt]);
            }
        }
    }
}

__global__ __launch_bounds__(256, 1) void resmlp_main(
    const uint16_t* __restrict__ H,
    const float* __restrict__ head_b,
    const uint16_t* __restrict__ ws,
    float* __restrict__ out)
{
    extern __shared__ __align__(16) uint16_t lds[];   // 6 x 25600 B ring
    const int tid = threadIdx.x;
    const int wave = tid >> 6, lane = tid & 63;
    const int hi = lane >> 5, ln = lane & 31;
    const int lane8 = lane * 8;
    const int batch0 = blockIdx.x * 256 + wave * 64;

    // ---- load resid = h0 from H (before ANY staging: clean vmcnt FIFO) ----
    float resid[2][5][16];
#pragma unroll
    for (int s = 0; s < 2; ++s)
#pragma unroll
        for (int mt = 0; mt < 5; ++mt) {
            const uint16_t* hp = H + (size_t)(batch0 + s * 32 + ln) * 160
                                   + mt * 32 + hi * 16;
            const u32x4 pa = *(const u32x4*)hp;
            const u32x4 pb = *(const u32x4*)(hp + 8);
            const uint32_t u[8] = {pa.x, pa.y, pa.z, pa.w, pb.x, pb.y, pb.z, pb.w};
#pragma unroll
            for (int j = 0; j < 8; ++j) {
                resid[s][mt][2 * j]     = __builtin_bit_cast(float, u[j] << 16);
                resid[s][mt][2 * j + 1] = __builtin_bit_cast(float, u[j] & 0xFFFF0000u);
            }
        }

    f32x16 zf;
#pragma unroll
    for (int r = 0; r < 16; ++r) zf[r] = 0.f;
    f32x16 acc[2][5];

    // stage unit u (0..63 layer halves, 64..65 head halves) into slot u%6
    auto do_stage = [&](int u) {
        int S, C;
        if (u < 64) { S = 245 + u * 25;        C = 25; }
        else        { S = 1845 + (u - 64) * 5; C = 5;  }
        const char* src = (const char*)ws + (size_t)S * 1024 + lane * 16;
        char* dst = (char*)lds + (u % 6) * SLOT_BYTES + lane * 16;
        for (int i = wave; i < C; i += 4)
            gl_lds16(src + (size_t)i * 1024, dst + i * 1024);
    };

    // ---- prologue: 4 units in flight, wait own 0,1, publish via barrier ----
    do_stage(0); do_stage(1); do_stage(2); do_stage(3);
    WAITVM(12);
    __builtin_amdgcn_s_barrier();

    // ---- 32 layers ----
    for (int L = 0; L < 32; ++L) {
        if (L <= 30) { do_stage(2 * L + 4); do_stage(2 * L + 5); }
        if (L > 0) {
#pragma unroll
            for (int s = 0; s < 2; ++s)
#pragma unroll
                for (int mt = 0; mt < 5; ++mt)
#pragma unroll
                    for (int r = 0; r < 16; ++r)
                        resid[s][mt][r] += fmaxf(acc[s][mt][r], 0.f);
        }
        const uint16_t* bufA = lds + ((2 * L) % 6) * SLOT_ELEMS;
        const uint16_t* bufB = lds + ((2 * L + 1) % 6) * SLOT_ELEMS;
        layer10<5>(bufA, bufB, acc, resid, zf, lane8);
        // wait own copies of NEXT phase's units, then publish
        if (L <= 29)      { WAITVM(12); }
        else if (L == 30) { WAITVM(2);  }
        else              { WAITVM(0);  }
        __builtin_amdgcn_s_barrier();
    }

    // ---- head (units 64,65 in slots 4,5) ----
#pragma unroll
    for (int s = 0; s < 2; ++s)
#pragma unroll
        for (int mt = 0; mt < 5; ++mt)
#pragma unroll
            for (int r = 0; r < 16; ++r)
                resid[s][mt][r] += fmaxf(acc[s][mt][r], 0.f);
    layer10<1>(lds + 4 * SLOT_ELEMS, lds + 5 * SLOT_ELEMS, acc, resid, zf, lane8);

    // epilogue: class = (r&3)+8*(r>>2)+4*hi  (valid classes < 10)
#pragma unroll
    for (int s = 0; s < 2; ++s) {
        float* op = out + (size_t)(batch0 + s * 32 + ln) * 10;
        if (hi == 0) {
            op[0] = acc[s][0][0] + head_b[0];
            op[1] = acc[s][0][1] + head_b[1];
            op[2] = acc[s][0][2] + head_b[2];
            op[3] = acc[s][0][3] + head_b[3];
            op[8] = acc[s][0][4] + head_b[8];
            op[9] = acc[s][0][5] + head_b[9];
        } else {
            op[4] = acc[s][0][0] + head_b[4];
            op[5] = acc[s][0][1] + head_b[5];
            op[6] = acc[s][0][2] + head_b[6];
            op[7] = acc[s][0][3] + head_b[7];
        }
    }
}

// ---------------------------------------------------------------------------
extern "C" void kernel_launch(void* const* d_in, const int* in_sizes, int n_in,
                              void* d_out, int out_size, void* d_ws, size_t ws_size,
                              hipStream_t stream) {
    (void)in_sizes; (void)n_in; (void)out_size; (void)ws_size;
    const float* x       = (const float*)d_in[0];
    const float* embed_w = (const float*)d_in[1];
    const float* embed_b = (const float*)d_in[2];
    const float* layer_w = (const float*)d_in[3];
    const float* head_w  = (const float*)d_in[4];
    const float* head_b  = (const float*)d_in[5];
    float* out = (float*)d_out;

    uint16_t* ws = (uint16_t*)d_ws;                       // frags: 1.86 MB
    uint16_t* H  = (uint16_t*)((char*)d_ws + H_OFFSET);   // h0 bf16: 21 MB

    const int ldsE = 3 * SLOT_BYTES;   // 76800 B  -> 2 blocks/CU
    const int ldsM = 6 * SLOT_BYTES;   // 153600 B -> 1 block/CU
    (void)hipFuncSetAttribute((const void*)resmlp_embed,
                              hipFuncAttributeMaxDynamicSharedMemorySize, ldsE);
    (void)hipFuncSetAttribute((const void*)resmlp_main,
                              hipFuncAttributeMaxDynamicSharedMemorySize, ldsM);

    resmlp_prep<<<(NFRAG_TOTAL + 3) / 4, 256, 0, stream>>>(embed_w, layer_w, head_w, ws);
    resmlp_embed<<<512, 256, ldsE, stream>>>(x, embed_b, ws, H);
    resmlp_main<<<256, 256, ldsM, stream>>>(H, head_b, ws, out);
}